// Round 7
// baseline (1359.943 us; speedup 1.0000x reference)
//
#include <hip/hip_runtime.h>
#include <hip/hip_bf16.h>

typedef __hip_bfloat16 bf16;
typedef __attribute__((ext_vector_type(8))) short short8;
typedef __attribute__((ext_vector_type(4))) float f32x4;

#define DEVI __device__ __forceinline__

static constexpr int Bb = 32;
static constexpr int Ss = 1024;
static constexpr int Hh = 768;
static constexpr float LNEPS = 1e-5f;

DEVI void async16(const bf16* g, bf16* l) {
    __builtin_amdgcn_global_load_lds(
        (const __attribute__((address_space(1))) unsigned int*)g,
        (__attribute__((address_space(3))) unsigned int*)l,
        16, 0, 0);
}

DEVI unsigned fkey(float f) {
    unsigned u = __float_as_uint(f);
    return (u & 0x80000000u) ? ~u : (u | 0x80000000u);
}
DEVI float funkey(unsigned k) {
    return (k & 0x80000000u) ? __uint_as_float(k ^ 0x80000000u) : __uint_as_float(~k);
}

// ---------------- GEMM: C[M,N] = epi( A[M,K] @ Bt[N,K]^T ) ----------------
// A,Bt bf16 row-major (row stride = K). 128x128 tile, BK=32, 256 thr = 4 waves (2x2).
#define EPI_BF16_BIAS  0
#define EPI_BF16_SCALE 1
#define EPI_F32        2
#define EPI_F32_RES    3

template<int EPI>
__global__ __launch_bounds__(256)
void gemm_bt(const bf16* __restrict__ A, const bf16* __restrict__ Bt,
             void* __restrict__ Cv, const float* __restrict__ bias,
             const float* __restrict__ res,
             int M, int N, int K,
             long sA, long sB, long sC, long sRes, float scale)
{
    __shared__ bf16 As[128 * 32];
    __shared__ bf16 Bs[128 * 32];

    const int z = blockIdx.z;
    A  += (long)z * sA;
    Bt += (long)z * sB;

    const int n0  = blockIdx.x * 128;
    const int m0  = blockIdx.y * 128;
    const int tid = threadIdx.x;
    const int lane = tid & 63;
    const int w  = tid >> 6;
    const int wr = w >> 1, wc = w & 1;

    f32x4 acc[4][4];
    #pragma unroll
    for (int i = 0; i < 4; ++i)
        #pragma unroll
        for (int j = 0; j < 4; ++j) acc[i][j] = (f32x4){0.f, 0.f, 0.f, 0.f};

    // staging: chunk c (16B) -> row c>>2, k-offset (c&3)*8 elems
    const int c0 = tid,        r0 = c0 >> 2, kc0 = (c0 & 3) * 8;
    const int c1 = tid + 256,  r1 = c1 >> 2, kc1 = (c1 & 3) * 8;

    const int fr_row = lane & 15;
    const int fr_k   = (lane >> 4) * 8;

    const int nK = K >> 5;
    for (int kt = 0; kt < nK; ++kt) {
        const int k0 = kt << 5;
        async16(&A [(long)(m0 + r0) * K + k0 + kc0], &As[c0 * 8]);
        async16(&A [(long)(m0 + r1) * K + k0 + kc1], &As[c1 * 8]);
        async16(&Bt[(long)(n0 + r0) * K + k0 + kc0], &Bs[c0 * 8]);
        async16(&Bt[(long)(n0 + r1) * K + k0 + kc1], &Bs[c1 * 8]);
        __syncthreads();   // compiler drains vmcnt before s_barrier

        short8 af[4], bfr[4];
        #pragma unroll
        for (int i = 0; i < 4; ++i) {
            af [i] = *(const short8*)&As[(wr * 64 + i * 16 + fr_row) * 32 + fr_k];
            bfr[i] = *(const short8*)&Bs[(wc * 64 + i * 16 + fr_row) * 32 + fr_k];
        }
        #pragma unroll
        for (int mi = 0; mi < 4; ++mi)
            #pragma unroll
            for (int ni = 0; ni < 4; ++ni)
                acc[mi][ni] = __builtin_amdgcn_mfma_f32_16x16x32_bf16(
                    af[mi], bfr[ni], acc[mi][ni], 0, 0, 0);
        __syncthreads();
    }

    // epilogue: C row = m0+wr*64+mi*16+(lane>>4)*4+r ; col = n0+wc*64+ni*16+(lane&15)
    #pragma unroll
    for (int mi = 0; mi < 4; ++mi) {
        #pragma unroll
        for (int ni = 0; ni < 4; ++ni) {
            const int col = n0 + wc * 64 + ni * 16 + (lane & 15);
            #pragma unroll
            for (int r = 0; r < 4; ++r) {
                const int row = m0 + wr * 64 + mi * 16 + (lane >> 4) * 4 + r;
                float v = acc[mi][ni][r];
                const long ci = (long)z * sC + (long)row * N + col;
                if constexpr (EPI == EPI_BF16_BIAS) {
                    ((bf16*)Cv)[ci] = __float2bfloat16(v + bias[col]);
                } else if constexpr (EPI == EPI_BF16_SCALE) {
                    ((bf16*)Cv)[ci] = __float2bfloat16(v * scale);
                } else if constexpr (EPI == EPI_F32) {
                    ((float*)Cv)[ci] = v;
                } else {
                    ((float*)Cv)[ci] = v + res[(long)z * sRes + (long)row * N + col];
                }
            }
        }
    }
}

// ---------------- elementwise / utility kernels ----------------

__global__ void cvt_bf16(const float* __restrict__ x, bf16* __restrict__ y, long n4) {
    long i = (long)blockIdx.x * 256 + threadIdx.x;
    if (i >= n4) return;
    float4 v = *(const float4*)&x[i * 4];
    union { bf16 h[4]; unsigned long long u; } pk;
    pk.h[0] = __float2bfloat16(v.x); pk.h[1] = __float2bfloat16(v.y);
    pk.h[2] = __float2bfloat16(v.z); pk.h[3] = __float2bfloat16(v.w);
    *(unsigned long long*)&y[i * 4] = pk.u;
}

// per z: in [R, C] -> out [C, R]
__global__ void transpose_bf16(const bf16* __restrict__ in, bf16* __restrict__ out,
                               int R, int C, long sIn, long sOut)
{
    __shared__ bf16 tile[32][33];
    const int z = blockIdx.z;
    in  += (long)z * sIn;
    out += (long)z * sOut;
    const int cb = blockIdx.x * 32, rb = blockIdx.y * 32;
    const int tx = threadIdx.x & 31, ty = threadIdx.x >> 5;
    #pragma unroll
    for (int i = 0; i < 4; ++i) {
        int r = ty + i * 8;
        tile[r][tx] = in[(long)(rb + r) * C + cb + tx];
    }
    __syncthreads();
    #pragma unroll
    for (int i = 0; i < 4; ++i) {
        int r = ty + i * 8;
        out[(long)(cb + r) * R + rb + tx] = tile[tx][r];
    }
}

template<int CNT>   // row width = CNT*256, in-place softmax over bf16 rows
__global__ void softmax_rows(bf16* __restrict__ P) {
    const int W = CNT * 256;
    bf16* p = P + (long)blockIdx.x * W;
    const int tid = threadIdx.x;
    float v[CNT];
    float mx = -3.0e38f;
    #pragma unroll
    for (int i = 0; i < CNT; ++i) {
        v[i] = __bfloat162float(p[tid + i * 256]);
        mx = fmaxf(mx, v[i]);
    }
    #pragma unroll
    for (int o = 32; o; o >>= 1) mx = fmaxf(mx, __shfl_xor(mx, o));
    __shared__ float sm[4], ss[4];
    if ((tid & 63) == 0) sm[tid >> 6] = mx;
    __syncthreads();
    mx = fmaxf(fmaxf(sm[0], sm[1]), fmaxf(sm[2], sm[3]));
    float s = 0.f;
    #pragma unroll
    for (int i = 0; i < CNT; ++i) { v[i] = __expf(v[i] - mx); s += v[i]; }
    #pragma unroll
    for (int o = 32; o; o >>= 1) s += __shfl_xor(s, o);
    if ((tid & 63) == 0) ss[tid >> 6] = s;
    __syncthreads();
    s = ss[0] + ss[1] + ss[2] + ss[3];
    const float inv = 1.0f / s;
    #pragma unroll
    for (int i = 0; i < CNT; ++i) p[tid + i * 256] = __float2bfloat16(v[i] * inv);
}

// per-batch LN stats (sum, sumsq) via block partials + float atomics
__global__ void ln_stats(const float* __restrict__ x, float* __restrict__ stats, int perB) {
    const int b = blockIdx.y;
    const float* xb = x + (long)b * perB;
    const int tid = threadIdx.x;
    const long base = (long)blockIdx.x * 4096;
    float s1 = 0.f, s2 = 0.f;
    #pragma unroll
    for (int i = 0; i < 4; ++i) {
        float4 v = *(const float4*)&xb[base + i * 1024 + tid * 4];
        s1 += v.x + v.y + v.z + v.w;
        s2 += v.x * v.x + v.y * v.y + v.z * v.z + v.w * v.w;
    }
    #pragma unroll
    for (int o = 32; o; o >>= 1) { s1 += __shfl_xor(s1, o); s2 += __shfl_xor(s2, o); }
    __shared__ float r1[4], r2[4];
    if ((tid & 63) == 0) { r1[tid >> 6] = s1; r2[tid >> 6] = s2; }
    __syncthreads();
    if (tid == 0) {
        atomicAdd(&stats[b * 2],     r1[0] + r1[1] + r1[2] + r1[3]);
        atomicAdd(&stats[b * 2 + 1], r2[0] + r2[1] + r2[2] + r2[3]);
    }
}

DEVI void ln_params(const float* stats, int b, float n, float& mu, float& rs) {
    mu = stats[b * 2] / n;
    float var = stats[b * 2 + 1] / n - mu * mu;
    rs = rsqrtf(fmaxf(var, 0.f) + LNEPS);
}

__global__ void ln_apply(const float* __restrict__ x, const float* __restrict__ stats,
                         bf16* __restrict__ y, int perB)
{
    const long i4 = ((long)blockIdx.x * 256 + threadIdx.x) * 4;
    const int b = (int)(i4 / perB);
    float mu, rs; ln_params(stats, b, (float)perB, mu, rs);
    float4 v = *(const float4*)&x[i4];
    union { bf16 h[4]; unsigned long long u; } pk;
    pk.h[0] = __float2bfloat16((v.x - mu) * rs);
    pk.h[1] = __float2bfloat16((v.y - mu) * rs);
    pk.h[2] = __float2bfloat16((v.z - mu) * rs);
    pk.h[3] = __float2bfloat16((v.w - mu) * rs);
    *(unsigned long long*)&y[i4] = pk.u;
}

// gate[b,s] = rs*( x[b,s,:].Wsg - mu*sum(Wsg) ) + bsg   (LN fused into the dot)
__global__ void gate_kernel(const float* __restrict__ xn, const float* __restrict__ Wsg,
                            const float* __restrict__ bsg, const float* __restrict__ stats2,
                            const float* __restrict__ sumW, float* __restrict__ gate)
{
    const long row = blockIdx.x;            // b*S + s
    const int b = (int)(row >> 10);
    const float* xr = xn + row * Hh;
    const int tid = threadIdx.x;
    float d = 0.f;
    #pragma unroll
    for (int j = 0; j < 3; ++j) d += xr[tid + j * 256] * Wsg[tid + j * 256];
    #pragma unroll
    for (int o = 32; o; o >>= 1) d += __shfl_xor(d, o);
    __shared__ float sr[4];
    if ((tid & 63) == 0) sr[tid >> 6] = d;
    __syncthreads();
    if (tid == 0) {
        float mu, rs; ln_params(stats2, b, (float)(Ss * Hh), mu, rs);
        gate[row] = rs * ((sr[0] + sr[1] + sr[2] + sr[3]) - mu * sumW[0]) + bsg[0];
    }
}

__global__ void pool_kernel(const float* __restrict__ xn, const float* __restrict__ gate,
                            const float* __restrict__ stats2, float* __restrict__ psum,
                            unsigned* __restrict__ pmax)
{
    const int b = blockIdx.y;
    const int s0 = blockIdx.x * 128;
    const int tid = threadIdx.x;
    float mu, rs; ln_params(stats2, b, (float)(Ss * Hh), mu, rs);
    const float* xb = xn + (long)b * (Ss * Hh);
    float sum[3] = {0.f, 0.f, 0.f};
    float mx[3]  = {-3e38f, -3e38f, -3e38f};
    for (int s = s0; s < s0 + 128; ++s) {
        float g = gate[(b << 10) + s];
        #pragma unroll
        for (int j = 0; j < 3; ++j) {
            float v = g * (xb[(long)s * Hh + tid + j * 256] - mu) * rs;
            sum[j] += v;
            mx[j] = fmaxf(mx[j], v);
        }
    }
    #pragma unroll
    for (int j = 0; j < 3; ++j) {
        atomicAdd(&psum[b * Hh + tid + j * 256], sum[j]);
        atomicMax(&pmax[b * Hh + tid + j * 256], fkey(mx[j]));
    }
}

__global__ void classifier(const float* __restrict__ psum, const unsigned* __restrict__ pmax,
                           const float* __restrict__ Wf, const float* __restrict__ bfn,
                           float* __restrict__ out)
{
    const int b = blockIdx.x, tid = threadIdx.x;
    float a0 = 0.f, a1 = 0.f, a2 = 0.f;
    for (int h = tid; h < Hh; h += 256) {
        float mean = psum[b * Hh + h] * (1.f / (float)Ss);
        float mxv  = funkey(pmax[b * Hh + h]);
        a0 += mean * Wf[0 * 1536 + h] + mxv * Wf[0 * 1536 + Hh + h];
        a1 += mean * Wf[1 * 1536 + h] + mxv * Wf[1 * 1536 + Hh + h];
        a2 += mean * Wf[2 * 1536 + h] + mxv * Wf[2 * 1536 + Hh + h];
    }
    #pragma unroll
    for (int o = 32; o; o >>= 1) {
        a0 += __shfl_xor(a0, o); a1 += __shfl_xor(a1, o); a2 += __shfl_xor(a2, o);
    }
    __shared__ float r[3][4];
    if ((tid & 63) == 0) { int w = tid >> 6; r[0][w] = a0; r[1][w] = a1; r[2][w] = a2; }
    __syncthreads();
    if (tid < 3) out[b * 3 + tid] = r[tid][0] + r[tid][1] + r[tid][2] + r[tid][3] + bfn[tid];
}

__global__ void init_ws(float* stats1, float* stats2, float* psum, unsigned* pmax,
                        float* sumW, const float* Wsg)
{
    const int tid = threadIdx.x;
    if (tid < 64) { stats1[tid] = 0.f; stats2[tid] = 0.f; }
    for (int i = tid; i < Bb * Hh; i += 256) { psum[i] = 0.f; pmax[i] = 0u; }
    float s = 0.f;
    for (int i = tid; i < Hh; i += 256) s += Wsg[i];
    #pragma unroll
    for (int o = 32; o; o >>= 1) s += __shfl_xor(s, o);
    __shared__ float sr[4];
    if ((tid & 63) == 0) sr[tid >> 6] = s;
    __syncthreads();
    if (tid == 0) sumW[0] = sr[0] + sr[1] + sr[2] + sr[3];
}

__global__ void sentinel_kernel(float* out, int n) {
    int i = blockIdx.x * 256 + threadIdx.x;
    if (i < n) out[i] = -12345.0f;
}

// ---------------- host launch ----------------
//
// Workspace plan (272.3 MB total, vs 424 MB in the crashing version):
//   W   : wq/wk/wv bf16               3.4 MB
//   X0  : tokens bf16 -> out_ln bf16  50.3 MB
//   X1  : Q  -> OF[lo] -> Qn  -> KnT  50.3 MB  (X1,X2 adjacent, no padding)
//   X2  : K  -> OF[hi] -> Kn  -> Sn   50.3 MB
//   X4  : VT -> QnT -> PnT            50.3 MB
//   SP  : [V|Vn in first 50.3MB] scores/P  67.1 MB
//   OF (fp32 out / out_n, 100.66 MB) == X1∪X2 exactly.

extern "C" void kernel_launch(void* const* d_in, const int* in_sizes, int n_in,
                              void* d_out, int out_size, void* d_ws, size_t ws_size,
                              hipStream_t stream)
{
    const float* tokens = (const float*)d_in[0];
    const float* Wq  = (const float*)d_in[1];
    const float* bq  = (const float*)d_in[2];
    const float* Wk  = (const float*)d_in[3];
    const float* bk  = (const float*)d_in[4];
    const float* Wv  = (const float*)d_in[5];
    const float* bv  = (const float*)d_in[6];
    const float* Wsg = (const float*)d_in[7];
    const float* bsg = (const float*)d_in[8];
    const float* Wf  = (const float*)d_in[9];
    const float* bfn = (const float*)d_in[10];
    float* out = (float*)d_out;

    const long BSH = (long)Bb * Ss * Hh;     // 25165824
    const long HH  = (long)Hh * Hh;          // 589824
    const long BSS = (long)Bb * Ss * Ss;     // 33554432
    const long SH  = (long)Ss * Hh;          // 786432
    const float SCALE = 1.0f / sqrtf((float)Hh);

    char* w = (char*)d_ws;
    size_t off = 0;
    auto alloc = [&](size_t bytes) -> void* {
        off = (off + 255) & ~(size_t)255;
        void* p = w + off;
        off += bytes;
        return p;
    };
    bf16*  wqB = (bf16*)alloc(HH * 2);
    bf16*  wkB = (bf16*)alloc(HH * 2);
    bf16*  wvB = (bf16*)alloc(HH * 2);
    bf16*  X0  = (bf16*)alloc(BSH * 2);
    bf16*  X1  = (bf16*)alloc(BSH * 2);      // BSH*2 is 256-multiple -> X2 contiguous
    bf16*  X2  = (bf16*)alloc(BSH * 2);
    bf16*  X4  = (bf16*)alloc(BSH * 2);
    bf16*  SP  = (bf16*)alloc(BSS * 2);
    float* stats1 = (float*)alloc(256);
    float* stats2 = (float*)alloc(256);
    float* sumW   = (float*)alloc(256);
    float* psum   = (float*)alloc((size_t)Bb * Hh * 4);
    unsigned* pmax = (unsigned*)alloc((size_t)Bb * Hh * 4);
    float* gate   = (float*)alloc((size_t)Bb * Ss * 4);
    const size_t need = off;
    (void)in_sizes; (void)n_in;

    if (ws_size < need) {
        // diagnostic: distinguishable clean failure instead of an OOB crash
        sentinel_kernel<<<1, 256, 0, stream>>>(out, out_size);
        return;
    }

    bf16*  tokB = X0;
    bf16*  Qb   = X1;
    bf16*  Kb   = X2;
    bf16*  Vb   = SP;          // V lives in the scores region (dead before scores write)
    bf16*  VT   = X4;
    float* OF   = (float*)X1;  // spans X1+X2 = BSH*4 bytes exactly

    init_ws<<<1, 256, 0, stream>>>(stats1, stats2, psum, pmax, sumW, Wsg);

    cvt_bf16<<<(int)(BSH / 1024), 256, 0, stream>>>(tokens, tokB, BSH / 4);
    cvt_bf16<<<(int)(HH / 1024), 256, 0, stream>>>(Wq, wqB, HH / 4);
    cvt_bf16<<<(int)(HH / 1024), 256, 0, stream>>>(Wk, wkB, HH / 4);
    cvt_bf16<<<(int)(HH / 1024), 256, 0, stream>>>(Wv, wvB, HH / 4);

    // ---- Q,K,V = tokens @ W^T + b  (bf16 out)
    {
        dim3 g(Hh / 128, (Bb * Ss) / 128, 1);
        gemm_bt<EPI_BF16_BIAS><<<g, 256, 0, stream>>>(tokB, wqB, Qb, bq, nullptr,
            Bb * Ss, Hh, Hh, 0, 0, 0, 0, 1.f);
        gemm_bt<EPI_BF16_BIAS><<<g, 256, 0, stream>>>(tokB, wkB, Kb, bk, nullptr,
            Bb * Ss, Hh, Hh, 0, 0, 0, 0, 1.f);
        gemm_bt<EPI_BF16_BIAS><<<g, 256, 0, stream>>>(tokB, wvB, Vb, bv, nullptr,
            Bb * Ss, Hh, Hh, 0, 0, 0, 0, 1.f);
    }
    // V^T per batch: [S,H] -> [H,S]   (V dead afterwards; its region joins SP)
    transpose_bf16<<<dim3(Hh / 32, Ss / 32, Bb), 256, 0, stream>>>(Vb, VT, Ss, Hh, SH, SH);

    // ---- scores = Q K^T * SCALE (bf16, overwrites V region too), softmax rows -> P
    gemm_bt<EPI_BF16_SCALE><<<dim3(Ss / 128, Ss / 128, Bb), 256, 0, stream>>>(
        Qb, Kb, SP, nullptr, nullptr, Ss, Ss, Hh, SH, SH, (long)Ss * Ss, 0, SCALE);
    softmax_rows<4><<<Bb * Ss, 256, 0, stream>>>(SP);

    // ---- out = P @ V  (A=P [S,S], Bt=V^T [H,S]) -> fp32 OF (over Q,K regions; both dead)
    gemm_bt<EPI_F32><<<dim3(Hh / 128, Ss / 128, Bb), 256, 0, stream>>>(
        SP, VT, OF, nullptr, nullptr, Ss, Hh, Ss, (long)Ss * Ss, SH, SH, 0, 1.f);

    // ---- LN1 (OF dead after ln_apply)
    ln_stats<<<dim3(192, Bb), 256, 0, stream>>>(OF, stats1, Ss * Hh);
    ln_apply<<<(int)(BSH / 1024), 256, 0, stream>>>(OF, stats1, tokB, Ss * Hh);

    // ---- Qn,Kn,Vn = out_ln @ W^T + b   (Vn into SP region; P dead)
    bf16* Qn = X1; bf16* Kn = X2; bf16* Vn = SP;
    {
        dim3 g(Hh / 128, (Bb * Ss) / 128, 1);
        gemm_bt<EPI_BF16_BIAS><<<g, 256, 0, stream>>>(tokB, wqB, Qn, bq, nullptr,
            Bb * Ss, Hh, Hh, 0, 0, 0, 0, 1.f);
        gemm_bt<EPI_BF16_BIAS><<<g, 256, 0, stream>>>(tokB, wkB, Kn, bk, nullptr,
            Bb * Ss, Hh, Hh, 0, 0, 0, 0, 1.f);
        gemm_bt<EPI_BF16_BIAS><<<g, 256, 0, stream>>>(tokB, wvB, Vn, bv, nullptr,
            Bb * Ss, Hh, Hh, 0, 0, 0, 0, 1.f);
    }

    // ---- Qn^T -> X4 (VT dead), then Kn^T -> X1 (Qn dead)
    bf16* QnT = X4;
    bf16* KnT = X1;
    transpose_bf16<<<dim3(Hh / 32, Ss / 32, Bb), 256, 0, stream>>>(Qn, QnT, Ss, Hh, SH, SH);
    transpose_bf16<<<dim3(Hh / 32, Ss / 32, Bb), 256, 0, stream>>>(Kn, KnT, Ss, Hh, SH, SH);

    // ---- Sn = Qn^T Kn * SCALE -> [B,H,H] bf16 into X2 (Kn dead), softmax -> Pn
    bf16* Sn = X2;
    gemm_bt<EPI_BF16_SCALE><<<dim3(Hh / 128, Hh / 128, Bb), 256, 0, stream>>>(
        QnT, KnT, Sn, nullptr, nullptr, Hh, Hh, Ss, SH, SH, HH, 0, SCALE);
    softmax_rows<3><<<Bb * Hh, 256, 0, stream>>>(Sn);

    // ---- Pn^T per batch: [H,H] -> [H,H] into X4 (QnT dead)
    bf16* PnT = X4;
    transpose_bf16<<<dim3(Hh / 32, Hh / 32, Bb), 256, 0, stream>>>(Sn, PnT, Hh, Hh, HH, HH);

    // ---- out_n = Vn @ Pn + tokens -> fp32 OF2 over X1∪X2 (KnT, Pn dead)
    float* OF2 = (float*)X1;
    gemm_bt<EPI_F32_RES><<<dim3(Hh / 128, Ss / 128, Bb), 256, 0, stream>>>(
        Vn, PnT, OF2, nullptr, tokens, Ss, Hh, Hh, SH, HH, SH, SH, 1.f);

    // ---- LN2 stats, gate, pool, classifier
    ln_stats<<<dim3(192, Bb), 256, 0, stream>>>(OF2, stats2, Ss * Hh);
    gate_kernel<<<Bb * Ss, 256, 0, stream>>>(OF2, Wsg, bsg, stats2, sumW, gate);
    pool_kernel<<<dim3(Ss / 128, Bb), 256, 0, stream>>>(OF2, gate, stats2, psum, pmax);
    classifier<<<Bb, 256, 0, stream>>>(psum, pmax, Wf, bfn, out);
}

// Round 8
// 1206.337 us; speedup vs baseline: 1.1273x; 1.1273x over previous
//
#include <hip/hip_runtime.h>
#include <hip/hip_bf16.h>

typedef __hip_bfloat16 bf16;
typedef unsigned short u16;
typedef __attribute__((ext_vector_type(8))) short short8;
typedef __attribute__((ext_vector_type(4))) float f32x4;

#define DEVI __device__ __forceinline__

static constexpr int Bb = 32;
static constexpr int Ss = 1024;
static constexpr int Hh = 768;
static constexpr float LNEPS = 1e-5f;

DEVI void async16(const bf16* g, bf16* l) {
    __builtin_amdgcn_global_load_lds(
        (const __attribute__((address_space(1))) unsigned int*)g,
        (__attribute__((address_space(3))) unsigned int*)l,
        16, 0, 0);
}

DEVI unsigned fkey(float f) {
    unsigned u = __float_as_uint(f);
    return (u & 0x80000000u) ? ~u : (u | 0x80000000u);
}
DEVI float funkey(unsigned k) {
    return (k & 0x80000000u) ? __uint_as_float(k ^ 0x80000000u) : __uint_as_float(~k);
}
DEVI u16 f2bu(float x) {
    bf16 h = __float2bfloat16(x);
    union { bf16 b; u16 u; } c; c.b = h; return c.u;
}

// ---------------- GEMM: C[M,N] = epi( A[M,K] @ Bt[N,K]^T ) ----------------
// A,Bt bf16 row-major (row stride = K). 128x128 tile, BK=32, 256 thr = 4 waves (2x2).
// + XCD-bijective tile remap (T1, L2 locality across batched grids)
// + LDS k-slot XOR swizzle (T2 via both-sides involution: pre-swizzled global
//   source feeding linear global_load_lds dest; ds_read applies same XOR).
#define EPI_BF16_BIAS  0
#define EPI_BF16_SCALE 1
#define EPI_F32        2
#define EPI_F32_RES    3

template<int EPI>
__global__ __launch_bounds__(256)
void gemm_bt(const bf16* __restrict__ A, const bf16* __restrict__ Bt,
             void* __restrict__ Cv, const float* __restrict__ bias,
             const float* __restrict__ res,
             int M, int N, int K,
             long sA, long sB, long sC, long sRes, float scale)
{
    __shared__ bf16 As[128 * 32];
    __shared__ bf16 Bs[128 * 32];

    // ---- XCD-bijective remap: consecutive HW blocks (round-robin over 8 XCDs)
    // get contiguous tile ranges -> same-batch panels stay in one XCD's L2.
    const int nx = gridDim.x, ny = gridDim.y;
    int bx, by, z;
    {
        const int nxy = nx * ny;
        const int nwg = nxy * gridDim.z;
        int t = blockIdx.x + nx * (blockIdx.y + ny * blockIdx.z);
        if ((nwg & 7) == 0) {                 // bijective only when nwg%8==0
            const int q = nwg >> 3;
            t = (t & 7) * q + (t >> 3);
        }
        z  = t / nxy;
        const int r2 = t - z * nxy;
        by = r2 / nx;
        bx = r2 - by * nx;
    }
    A  += (long)z * sA;
    Bt += (long)z * sB;

    const int n0  = bx * 128;
    const int m0  = by * 128;
    const int tid = threadIdx.x;
    const int lane = tid & 63;
    const int w  = tid >> 6;
    const int wr = w >> 1, wc = w & 1;

    f32x4 acc[4][4];
    #pragma unroll
    for (int i = 0; i < 4; ++i)
        #pragma unroll
        for (int j = 0; j < 4; ++j) acc[i][j] = (f32x4){0.f, 0.f, 0.f, 0.f};

    // staging: chunk c (16B) -> row c>>2, k-slot (c&3); global k-slot XOR'd by
    // (row>>1)&3 so the linear LDS layout is bank-spread on the fragment read.
    const int c0 = tid,        r0 = c0 >> 2, kc0 = (((c0 & 3) ^ ((r0 >> 1) & 3)) * 8);
    const int c1 = tid + 256,  r1 = c1 >> 2, kc1 = (((c1 & 3) ^ ((r1 >> 1) & 3)) * 8);

    const int fr_row = lane & 15;
    const int kk = (((lane >> 4) ^ ((fr_row >> 1) & 3)) * 8);   // swizzled k-slot

    const int nK = K >> 5;
    for (int kt = 0; kt < nK; ++kt) {
        const int k0 = kt << 5;
        async16(&A [(long)(m0 + r0) * K + k0 + kc0], &As[c0 * 8]);
        async16(&A [(long)(m0 + r1) * K + k0 + kc1], &As[c1 * 8]);
        async16(&Bt[(long)(n0 + r0) * K + k0 + kc0], &Bs[c0 * 8]);
        async16(&Bt[(long)(n0 + r1) * K + k0 + kc1], &Bs[c1 * 8]);
        __syncthreads();   // compiler drains vmcnt before s_barrier

        short8 af[4], bfr[4];
        #pragma unroll
        for (int i = 0; i < 4; ++i) {
            af [i] = *(const short8*)&As[(wr * 64 + i * 16 + fr_row) * 32 + kk];
            bfr[i] = *(const short8*)&Bs[(wc * 64 + i * 16 + fr_row) * 32 + kk];
        }
        #pragma unroll
        for (int mi = 0; mi < 4; ++mi)
            #pragma unroll
            for (int ni = 0; ni < 4; ++ni)
                acc[mi][ni] = __builtin_amdgcn_mfma_f32_16x16x32_bf16(
                    af[mi], bfr[ni], acc[mi][ni], 0, 0, 0);
        __syncthreads();
    }

    // epilogue: C row = m0+wr*64+mi*16+(lane>>4)*4+r ; col = n0+wc*64+ni*16+(lane&15)
    #pragma unroll
    for (int mi = 0; mi < 4; ++mi) {
        #pragma unroll
        for (int ni = 0; ni < 4; ++ni) {
            const int col = n0 + wc * 64 + ni * 16 + (lane & 15);
            #pragma unroll
            for (int r = 0; r < 4; ++r) {
                const int row = m0 + wr * 64 + mi * 16 + (lane >> 4) * 4 + r;
                float v = acc[mi][ni][r];
                const long ci = (long)z * sC + (long)row * N + col;
                if constexpr (EPI == EPI_BF16_BIAS) {
                    ((bf16*)Cv)[ci] = __float2bfloat16(v + bias[col]);
                } else if constexpr (EPI == EPI_BF16_SCALE) {
                    ((bf16*)Cv)[ci] = __float2bfloat16(v * scale);
                } else if constexpr (EPI == EPI_F32) {
                    ((float*)Cv)[ci] = v;
                } else {
                    ((float*)Cv)[ci] = v + res[(long)z * sRes + (long)row * N + col];
                }
            }
        }
    }
}

// ---------------- elementwise / utility kernels ----------------

__global__ void cvt_bf16(const float* __restrict__ x, bf16* __restrict__ y, long n4) {
    long i = (long)blockIdx.x * 256 + threadIdx.x;
    if (i >= n4) return;
    float4 v = *(const float4*)&x[i * 4];
    union { bf16 h[4]; unsigned long long u; } pk;
    pk.h[0] = __float2bfloat16(v.x); pk.h[1] = __float2bfloat16(v.y);
    pk.h[2] = __float2bfloat16(v.z); pk.h[3] = __float2bfloat16(v.w);
    *(unsigned long long*)&y[i * 4] = pk.u;
}

// per z: in [R, C] -> out [C, R]; 64x64 tiles, short4 (8B) global accesses.
// R, C must be multiples of 64 (S=1024, H=768 both are).
__global__ void transpose_bf16(const bf16* __restrict__ in_, bf16* __restrict__ out_,
                               int R, int C, long sIn, long sOut)
{
    __shared__ u16 tile[64][70];    // pad 70: store-phase LDS reads <=2-way
    const u16* in  = (const u16*)in_  + (long)blockIdx.z * sIn;
    u16*       out = (u16*)out_       + (long)blockIdx.z * sOut;
    const int cb = blockIdx.x * 64, rb = blockIdx.y * 64;
    const int lx = threadIdx.x & 15, ly = threadIdx.x >> 4;
    #pragma unroll
    for (int i = 0; i < 4; ++i) {
        const int r = ly + i * 16;
        ushort4 v = *(const ushort4*)&in[(long)(rb + r) * C + cb + lx * 4];
        *(unsigned*)&tile[r][lx * 4]     = (unsigned)v.x | ((unsigned)v.y << 16);
        *(unsigned*)&tile[r][lx * 4 + 2] = (unsigned)v.z | ((unsigned)v.w << 16);
    }
    __syncthreads();
    #pragma unroll
    for (int i = 0; i < 4; ++i) {
        const int ro = ly + i * 16;
        ushort4 o;
        o.x = tile[lx * 4 + 0][ro];
        o.y = tile[lx * 4 + 1][ro];
        o.z = tile[lx * 4 + 2][ro];
        o.w = tile[lx * 4 + 3][ro];
        *(ushort4*)&out[(long)(cb + ro) * R + rb + lx * 4] = o;
    }
}

template<int W>   // row width (1024 or 768), in-place softmax over bf16 rows
__global__ void softmax_rows(bf16* __restrict__ P) {
    constexpr int NV = W / 4;                       // ushort4 chunks per row
    u16* p = (u16*)(P + (long)blockIdx.x * W);
    const int tid = threadIdx.x;
    const bool act = tid < NV;
    float v[4];
    float mx = -3.0e38f;
    if (act) {
        ushort4 u4 = ((const ushort4*)p)[tid];
        v[0] = __uint_as_float((unsigned)u4.x << 16);
        v[1] = __uint_as_float((unsigned)u4.y << 16);
        v[2] = __uint_as_float((unsigned)u4.z << 16);
        v[3] = __uint_as_float((unsigned)u4.w << 16);
        mx = fmaxf(fmaxf(v[0], v[1]), fmaxf(v[2], v[3]));
    }
    #pragma unroll
    for (int o = 32; o; o >>= 1) mx = fmaxf(mx, __shfl_xor(mx, o));
    __shared__ float sm[4], ss[4];
    if ((tid & 63) == 0) sm[tid >> 6] = mx;
    __syncthreads();
    mx = fmaxf(fmaxf(sm[0], sm[1]), fmaxf(sm[2], sm[3]));
    float s = 0.f;
    if (act) {
        #pragma unroll
        for (int j = 0; j < 4; ++j) { v[j] = __expf(v[j] - mx); s += v[j]; }
    }
    #pragma unroll
    for (int o = 32; o; o >>= 1) s += __shfl_xor(s, o);
    if ((tid & 63) == 0) ss[tid >> 6] = s;
    __syncthreads();
    s = ss[0] + ss[1] + ss[2] + ss[3];
    const float inv = 1.0f / s;
    if (act) {
        ushort4 o4;
        o4.x = f2bu(v[0] * inv);
        o4.y = f2bu(v[1] * inv);
        o4.z = f2bu(v[2] * inv);
        o4.w = f2bu(v[3] * inv);
        ((ushort4*)p)[tid] = o4;
    }
}

// per-batch LN stats (sum, sumsq) via block partials + float atomics
__global__ void ln_stats(const float* __restrict__ x, float* __restrict__ stats, int perB) {
    const int b = blockIdx.y;
    const float* xb = x + (long)b * perB;
    const int tid = threadIdx.x;
    const long base = (long)blockIdx.x * 4096;
    float s1 = 0.f, s2 = 0.f;
    #pragma unroll
    for (int i = 0; i < 4; ++i) {
        float4 v = *(const float4*)&xb[base + i * 1024 + tid * 4];
        s1 += v.x + v.y + v.z + v.w;
        s2 += v.x * v.x + v.y * v.y + v.z * v.z + v.w * v.w;
    }
    #pragma unroll
    for (int o = 32; o; o >>= 1) { s1 += __shfl_xor(s1, o); s2 += __shfl_xor(s2, o); }
    __shared__ float r1[4], r2[4];
    if ((tid & 63) == 0) { r1[tid >> 6] = s1; r2[tid >> 6] = s2; }
    __syncthreads();
    if (tid == 0) {
        atomicAdd(&stats[b * 2],     r1[0] + r1[1] + r1[2] + r1[3]);
        atomicAdd(&stats[b * 2 + 1], r2[0] + r2[1] + r2[2] + r2[3]);
    }
}

DEVI void ln_params(const float* stats, int b, float n, float& mu, float& rs) {
    mu = stats[b * 2] / n;
    float var = stats[b * 2 + 1] / n - mu * mu;
    rs = rsqrtf(fmaxf(var, 0.f) + LNEPS);
}

__global__ void ln_apply(const float* __restrict__ x, const float* __restrict__ stats,
                         bf16* __restrict__ y, int perB)
{
    const long i4 = ((long)blockIdx.x * 256 + threadIdx.x) * 4;
    const int b = (int)(i4 / perB);
    float mu, rs; ln_params(stats, b, (float)perB, mu, rs);
    float4 v = *(const float4*)&x[i4];
    union { bf16 h[4]; unsigned long long u; } pk;
    pk.h[0] = __float2bfloat16((v.x - mu) * rs);
    pk.h[1] = __float2bfloat16((v.y - mu) * rs);
    pk.h[2] = __float2bfloat16((v.z - mu) * rs);
    pk.h[3] = __float2bfloat16((v.w - mu) * rs);
    *(unsigned long long*)&y[i4] = pk.u;
}

// gate[b,s] = rs*( x[b,s,:].Wsg - mu*sum(Wsg) ) + bsg   (LN fused into the dot)
__global__ void gate_kernel(const float* __restrict__ xn, const float* __restrict__ Wsg,
                            const float* __restrict__ bsg, const float* __restrict__ stats2,
                            const float* __restrict__ sumW, float* __restrict__ gate)
{
    const long row = blockIdx.x;            // b*S + s
    const int b = (int)(row >> 10);
    const float* xr = xn + row * Hh;
    const int tid = threadIdx.x;
    float d = 0.f;
    #pragma unroll
    for (int j = 0; j < 3; ++j) d += xr[tid + j * 256] * Wsg[tid + j * 256];
    #pragma unroll
    for (int o = 32; o; o >>= 1) d += __shfl_xor(d, o);
    __shared__ float sr[4];
    if ((tid & 63) == 0) sr[tid >> 6] = d;
    __syncthreads();
    if (tid == 0) {
        float mu, rs; ln_params(stats2, b, (float)(Ss * Hh), mu, rs);
        gate[row] = rs * ((sr[0] + sr[1] + sr[2] + sr[3]) - mu * sumW[0]) + bsg[0];
    }
}

__global__ void pool_kernel(const float* __restrict__ xn, const float* __restrict__ gate,
                            const float* __restrict__ stats2, float* __restrict__ psum,
                            unsigned* __restrict__ pmax)
{
    const int b = blockIdx.y;
    const int s0 = blockIdx.x * 128;
    const int tid = threadIdx.x;
    float mu, rs; ln_params(stats2, b, (float)(Ss * Hh), mu, rs);
    const float* xb = xn + (long)b * (Ss * Hh);
    float sum[3] = {0.f, 0.f, 0.f};
    float mx[3]  = {-3e38f, -3e38f, -3e38f};
    for (int s = s0; s < s0 + 128; ++s) {
        float g = gate[(b << 10) + s];
        #pragma unroll
        for (int j = 0; j < 3; ++j) {
            float v = g * (xb[(long)s * Hh + tid + j * 256] - mu) * rs;
            sum[j] += v;
            mx[j] = fmaxf(mx[j], v);
        }
    }
    #pragma unroll
    for (int j = 0; j < 3; ++j) {
        atomicAdd(&psum[b * Hh + tid + j * 256], sum[j]);
        atomicMax(&pmax[b * Hh + tid + j * 256], fkey(mx[j]));
    }
}

__global__ void classifier(const float* __restrict__ psum, const unsigned* __restrict__ pmax,
                           const float* __restrict__ Wf, const float* __restrict__ bfn,
                           float* __restrict__ out)
{
    const int b = blockIdx.x, tid = threadIdx.x;
    float a0 = 0.f, a1 = 0.f, a2 = 0.f;
    for (int h = tid; h < Hh; h += 256) {
        float mean = psum[b * Hh + h] * (1.f / (float)Ss);
        float mxv  = funkey(pmax[b * Hh + h]);
        a0 += mean * Wf[0 * 1536 + h] + mxv * Wf[0 * 1536 + Hh + h];
        a1 += mean * Wf[1 * 1536 + h] + mxv * Wf[1 * 1536 + Hh + h];
        a2 += mean * Wf[2 * 1536 + h] + mxv * Wf[2 * 1536 + Hh + h];
    }
    #pragma unroll
    for (int o = 32; o; o >>= 1) {
        a0 += __shfl_xor(a0, o); a1 += __shfl_xor(a1, o); a2 += __shfl_xor(a2, o);
    }
    __shared__ float r[3][4];
    if ((tid & 63) == 0) { int w = tid >> 6; r[0][w] = a0; r[1][w] = a1; r[2][w] = a2; }
    __syncthreads();
    if (tid < 3) out[b * 3 + tid] = r[tid][0] + r[tid][1] + r[tid][2] + r[tid][3] + bfn[tid];
}

__global__ void init_ws(float* stats1, float* stats2, float* psum, unsigned* pmax,
                        float* sumW, const float* Wsg)
{
    const int tid = threadIdx.x;
    if (tid < 64) { stats1[tid] = 0.f; stats2[tid] = 0.f; }
    for (int i = tid; i < Bb * Hh; i += 256) { psum[i] = 0.f; pmax[i] = 0u; }
    float s = 0.f;
    for (int i = tid; i < Hh; i += 256) s += Wsg[i];
    #pragma unroll
    for (int o = 32; o; o >>= 1) s += __shfl_xor(s, o);
    __shared__ float sr[4];
    if ((tid & 63) == 0) sr[tid >> 6] = s;
    __syncthreads();
    if (tid == 0) sumW[0] = sr[0] + sr[1] + sr[2] + sr[3];
}

__global__ void sentinel_kernel(float* out, int n) {
    int i = blockIdx.x * 256 + threadIdx.x;
    if (i < n) out[i] = -12345.0f;
}

// ---------------- host launch ----------------
//
// Workspace plan (272.3 MB, verified passing in R7):
//   W   : wq/wk/wv bf16               3.4 MB
//   X0  : tokens bf16 -> out_ln bf16  50.3 MB
//   X1  : Q  -> OF[lo] -> Qn  -> KnT  50.3 MB  (X1,X2 adjacent, no padding)
//   X2  : K  -> OF[hi] -> Kn  -> Sn   50.3 MB
//   X4  : VT -> QnT -> PnT            50.3 MB
//   SP  : [V|Vn in first 50.3MB] scores/P  67.1 MB
//   OF (fp32 out / out_n, 100.66 MB) == X1∪X2 exactly.

extern "C" void kernel_launch(void* const* d_in, const int* in_sizes, int n_in,
                              void* d_out, int out_size, void* d_ws, size_t ws_size,
                              hipStream_t stream)
{
    const float* tokens = (const float*)d_in[0];
    const float* Wq  = (const float*)d_in[1];
    const float* bq  = (const float*)d_in[2];
    const float* Wk  = (const float*)d_in[3];
    const float* bk  = (const float*)d_in[4];
    const float* Wv  = (const float*)d_in[5];
    const float* bv  = (const float*)d_in[6];
    const float* Wsg = (const float*)d_in[7];
    const float* bsg = (const float*)d_in[8];
    const float* Wf  = (const float*)d_in[9];
    const float* bfn = (const float*)d_in[10];
    float* out = (float*)d_out;

    const long BSH = (long)Bb * Ss * Hh;     // 25165824
    const long HH  = (long)Hh * Hh;          // 589824
    const long BSS = (long)Bb * Ss * Ss;     // 33554432
    const long SH  = (long)Ss * Hh;          // 786432
    const float SCALE = 1.0f / sqrtf((float)Hh);

    char* w = (char*)d_ws;
    size_t off = 0;
    auto alloc = [&](size_t bytes) -> void* {
        off = (off + 255) & ~(size_t)255;
        void* p = w + off;
        off += bytes;
        return p;
    };
    bf16*  wqB = (bf16*)alloc(HH * 2);
    bf16*  wkB = (bf16*)alloc(HH * 2);
    bf16*  wvB = (bf16*)alloc(HH * 2);
    bf16*  X0  = (bf16*)alloc(BSH * 2);
    bf16*  X1  = (bf16*)alloc(BSH * 2);      // BSH*2 is 256-multiple -> X2 contiguous
    bf16*  X2  = (bf16*)alloc(BSH * 2);
    bf16*  X4  = (bf16*)alloc(BSH * 2);
    bf16*  SP  = (bf16*)alloc(BSS * 2);
    float* stats1 = (float*)alloc(256);
    float* stats2 = (float*)alloc(256);
    float* sumW   = (float*)alloc(256);
    float* psum   = (float*)alloc((size_t)Bb * Hh * 4);
    unsigned* pmax = (unsigned*)alloc((size_t)Bb * Hh * 4);
    float* gate   = (float*)alloc((size_t)Bb * Ss * 4);
    const size_t need = off;
    (void)in_sizes; (void)n_in;

    if (ws_size < need) {
        // diagnostic: distinguishable clean failure instead of an OOB crash
        sentinel_kernel<<<1, 256, 0, stream>>>(out, out_size);
        return;
    }

    bf16*  tokB = X0;
    bf16*  Qb   = X1;
    bf16*  Kb   = X2;
    bf16*  Vb   = SP;          // V lives in the scores region (dead before scores write)
    bf16*  VT   = X4;
    float* OF   = (float*)X1;  // spans X1+X2 = BSH*4 bytes exactly

    init_ws<<<1, 256, 0, stream>>>(stats1, stats2, psum, pmax, sumW, Wsg);

    cvt_bf16<<<(int)(BSH / 1024), 256, 0, stream>>>(tokens, tokB, BSH / 4);
    cvt_bf16<<<(int)(HH / 1024), 256, 0, stream>>>(Wq, wqB, HH / 4);
    cvt_bf16<<<(int)(HH / 1024), 256, 0, stream>>>(Wk, wkB, HH / 4);
    cvt_bf16<<<(int)(HH / 1024), 256, 0, stream>>>(Wv, wvB, HH / 4);

    // ---- Q,K,V = tokens @ W^T + b  (bf16 out)
    {
        dim3 g(Hh / 128, (Bb * Ss) / 128, 1);
        gemm_bt<EPI_BF16_BIAS><<<g, 256, 0, stream>>>(tokB, wqB, Qb, bq, nullptr,
            Bb * Ss, Hh, Hh, 0, 0, 0, 0, 1.f);
        gemm_bt<EPI_BF16_BIAS><<<g, 256, 0, stream>>>(tokB, wkB, Kb, bk, nullptr,
            Bb * Ss, Hh, Hh, 0, 0, 0, 0, 1.f);
        gemm_bt<EPI_BF16_BIAS><<<g, 256, 0, stream>>>(tokB, wvB, Vb, bv, nullptr,
            Bb * Ss, Hh, Hh, 0, 0, 0, 0, 1.f);
    }
    // V^T per batch: [S,H] -> [H,S]   (V dead afterwards; its region joins SP)
    transpose_bf16<<<dim3(Hh / 64, Ss / 64, Bb), 256, 0, stream>>>(Vb, VT, Ss, Hh, SH, SH);

    // ---- scores = Q K^T * SCALE (bf16, overwrites V region too), softmax rows -> P
    gemm_bt<EPI_BF16_SCALE><<<dim3(Ss / 128, Ss / 128, Bb), 256, 0, stream>>>(
        Qb, Kb, SP, nullptr, nullptr, Ss, Ss, Hh, SH, SH, (long)Ss * Ss, 0, SCALE);
    softmax_rows<1024><<<Bb * Ss, 256, 0, stream>>>(SP);

    // ---- out = P @ V  (A=P [S,S], Bt=V^T [H,S]) -> fp32 OF (over Q,K regions; both dead)
    gemm_bt<EPI_F32><<<dim3(Hh / 128, Ss / 128, Bb), 256, 0, stream>>>(
        SP, VT, OF, nullptr, nullptr, Ss, Hh, Ss, (long)Ss * Ss, SH, SH, 0, 1.f);

    // ---- LN1 (OF dead after ln_apply)
    ln_stats<<<dim3(192, Bb), 256, 0, stream>>>(OF, stats1, Ss * Hh);
    ln_apply<<<(int)(BSH / 1024), 256, 0, stream>>>(OF, stats1, tokB, Ss * Hh);

    // ---- Qn,Kn,Vn = out_ln @ W^T + b   (Vn into SP region; P dead)
    bf16* Qn = X1; bf16* Kn = X2; bf16* Vn = SP;
    {
        dim3 g(Hh / 128, (Bb * Ss) / 128, 1);
        gemm_bt<EPI_BF16_BIAS><<<g, 256, 0, stream>>>(tokB, wqB, Qn, bq, nullptr,
            Bb * Ss, Hh, Hh, 0, 0, 0, 0, 1.f);
        gemm_bt<EPI_BF16_BIAS><<<g, 256, 0, stream>>>(tokB, wkB, Kn, bk, nullptr,
            Bb * Ss, Hh, Hh, 0, 0, 0, 0, 1.f);
        gemm_bt<EPI_BF16_BIAS><<<g, 256, 0, stream>>>(tokB, wvB, Vn, bv, nullptr,
            Bb * Ss, Hh, Hh, 0, 0, 0, 0, 1.f);
    }

    // ---- Qn^T -> X4 (VT dead), then Kn^T -> X1 (Qn dead)
    bf16* QnT = X4;
    bf16* KnT = X1;
    transpose_bf16<<<dim3(Hh / 64, Ss / 64, Bb), 256, 0, stream>>>(Qn, QnT, Ss, Hh, SH, SH);
    transpose_bf16<<<dim3(Hh / 64, Ss / 64, Bb), 256, 0, stream>>>(Kn, KnT, Ss, Hh, SH, SH);

    // ---- Sn = Qn^T Kn * SCALE -> [B,H,H] bf16 into X2 (Kn dead), softmax -> Pn
    bf16* Sn = X2;
    gemm_bt<EPI_BF16_SCALE><<<dim3(Hh / 128, Hh / 128, Bb), 256, 0, stream>>>(
        QnT, KnT, Sn, nullptr, nullptr, Hh, Hh, Ss, SH, SH, HH, 0, SCALE);
    softmax_rows<768><<<Bb * Hh, 256, 0, stream>>>(Sn);

    // ---- Pn^T per batch: [H,H] -> [H,H] into X4 (QnT dead)
    bf16* PnT = X4;
    transpose_bf16<<<dim3(Hh / 64, Hh / 64, Bb), 256, 0, stream>>>(Sn, PnT, Hh, Hh, HH, HH);

    // ---- out_n = Vn @ Pn + tokens -> fp32 OF2 over X1∪X2 (KnT, Pn dead)
    float* OF2 = (float*)X1;
    gemm_bt<EPI_F32_RES><<<dim3(Hh / 128, Ss / 128, Bb), 256, 0, stream>>>(
        Vn, PnT, OF2, nullptr, tokens, Ss, Hh, Hh, SH, HH, SH, SH, 1.f);

    // ---- LN2 stats, gate, pool, classifier
    ln_stats<<<dim3(192, Bb), 256, 0, stream>>>(OF2, stats2, Ss * Hh);
    gate_kernel<<<Bb * Ss, 256, 0, stream>>>(OF2, Wsg, bsg, stats2, sumW, gate);
    pool_kernel<<<dim3(Ss / 128, Bb), 256, 0, stream>>>(OF2, gate, stats2, psum, pmax);
    classifier<<<Bb, 256, 0, stream>>>(psum, pmax, Wf, bfn, out);
}

// Round 12
// 1136.064 us; speedup vs baseline: 1.1971x; 1.0619x over previous
//
#include <hip/hip_runtime.h>
#include <hip/hip_bf16.h>

typedef __hip_bfloat16 bf16;
typedef unsigned short u16;
typedef __attribute__((ext_vector_type(8))) short short8;
typedef __attribute__((ext_vector_type(4))) float f32x4;

#define DEVI __device__ __forceinline__

static constexpr int Bb = 32;
static constexpr int Ss = 1024;
static constexpr int Hh = 768;
static constexpr float LNEPS = 1e-5f;

DEVI void async16(const bf16* g, bf16* l) {
    __builtin_amdgcn_global_load_lds(
        (const __attribute__((address_space(1))) unsigned int*)g,
        (__attribute__((address_space(3))) unsigned int*)l,
        16, 0, 0);
}

DEVI unsigned fkey(float f) {
    unsigned u = __float_as_uint(f);
    return (u & 0x80000000u) ? ~u : (u | 0x80000000u);
}
DEVI float funkey(unsigned k) {
    return (k & 0x80000000u) ? __uint_as_float(k ^ 0x80000000u) : __uint_as_float(~k);
}
DEVI u16 f2bu(float x) {
    bf16 h = __float2bfloat16(x);
    union { bf16 b; u16 u; } c; c.b = h; return c.u;
}

// ---------------- GEMM: C[M,N] = epi( A[M,K] @ Bt[N,K]^T ) ----------------
// A,Bt bf16 row-major (row stride = K). 128x128 tile, BK=32, 256 thr = 4 waves (2x2).
// R8-verified: XCD-bijective remap (FETCH 342->103MB), k-slot XOR swizzle
// (BANK_CONFLICT 6.29M->0).
// R9: 2-phase LDS double-buffer (T3-minimum): prefetch tile t+1 before
// compute of tile t; ONE barrier per K-step whose vmcnt(0) drain lands
// AFTER the MFMAs -> HBM latency overlaps compute (was fully exposed).
#define EPI_BF16_BIAS  0
#define EPI_BF16_SCALE 1
#define EPI_F32        2
#define EPI_F32_RES    3

template<int EPI>
__global__ __launch_bounds__(256)
void gemm_bt(const bf16* __restrict__ A, const bf16* __restrict__ Bt,
             void* __restrict__ Cv, const float* __restrict__ bias,
             const float* __restrict__ res,
             int M, int N, int K,
             long sA, long sB, long sC, long sRes, float scale)
{
    __shared__ bf16 As[2][128 * 32];   // 2 x 8KB
    __shared__ bf16 Bs[2][128 * 32];   // total 32KB -> 5 blocks/CU by LDS

    // ---- XCD-bijective remap: consecutive HW blocks (round-robin over 8 XCDs)
    // get contiguous tile ranges -> same-batch panels stay in one XCD's L2.
    const int nx = gridDim.x, ny = gridDim.y;
    int bx, by, z;
    {
        const int nxy = nx * ny;
        const int nwg = nxy * gridDim.z;
        int t = blockIdx.x + nx * (blockIdx.y + ny * blockIdx.z);
        if ((nwg & 7) == 0) {                 // bijective only when nwg%8==0
            const int q = nwg >> 3;
            t = (t & 7) * q + (t >> 3);
        }
        z  = t / nxy;
        const int r2 = t - z * nxy;
        by = r2 / nx;
        bx = r2 - by * nx;
    }
    A  += (long)z * sA;
    Bt += (long)z * sB;

    const int n0  = bx * 128;
    const int m0  = by * 128;
    const int tid = threadIdx.x;
    const int lane = tid & 63;
    const int w  = tid >> 6;
    const int wr = w >> 1, wc = w & 1;

    f32x4 acc[4][4];
    #pragma unroll
    for (int i = 0; i < 4; ++i)
        #pragma unroll
        for (int j = 0; j < 4; ++j) acc[i][j] = (f32x4){0.f, 0.f, 0.f, 0.f};

    // staging: chunk c (16B) -> row c>>2, k-slot (c&3); global k-slot XOR'd by
    // (row>>1)&3 so the linear LDS layout is bank-spread on the fragment read.
    const int c0 = tid,        r0 = c0 >> 2, kc0 = (((c0 & 3) ^ ((r0 >> 1) & 3)) * 8);
    const int c1 = tid + 256,  r1 = c1 >> 2, kc1 = (((c1 & 3) ^ ((r1 >> 1) & 3)) * 8);

    const int fr_row = lane & 15;
    const int kk = (((lane >> 4) ^ ((fr_row >> 1) & 3)) * 8);   // swizzled k-slot

    const long aBase0 = (long)(m0 + r0) * K + kc0;
    const long aBase1 = (long)(m0 + r1) * K + kc1;
    const long bBase0 = (long)(n0 + r0) * K + kc0;
    const long bBase1 = (long)(n0 + r1) * K + kc1;

    auto STAGE = [&](int buf, int kt) {
        const int k0 = kt << 5;
        async16(&A [aBase0 + k0], &As[buf][c0 * 8]);
        async16(&A [aBase1 + k0], &As[buf][c1 * 8]);
        async16(&Bt[bBase0 + k0], &Bs[buf][c0 * 8]);
        async16(&Bt[bBase1 + k0], &Bs[buf][c1 * 8]);
    };

    const int nK = K >> 5;
    STAGE(0, 0);
    __syncthreads();               // drain prologue stage (vmcnt(0) + barrier)

    int cur = 0;
    for (int kt = 0; kt < nK; ++kt) {
        if (kt + 1 < nK) STAGE(cur ^ 1, kt + 1);   // prefetch next tile (async)

        short8 af[4], bfr[4];
        #pragma unroll
        for (int i = 0; i < 4; ++i) {
            af [i] = *(const short8*)&As[cur][(wr * 64 + i * 16 + fr_row) * 32 + kk];
            bfr[i] = *(const short8*)&Bs[cur][(wc * 64 + i * 16 + fr_row) * 32 + kk];
        }
        #pragma unroll
        for (int mi = 0; mi < 4; ++mi)
            #pragma unroll
            for (int ni = 0; ni < 4; ++ni)
                acc[mi][ni] = __builtin_amdgcn_mfma_f32_16x16x32_bf16(
                    af[mi], bfr[ni], acc[mi][ni], 0, 0, 0);

        __syncthreads();           // drains prefetch vmcnt AFTER compute; orders
        cur ^= 1;                  // buf reuse across iterations
    }

    // epilogue: C row = m0+wr*64+mi*16+(lane>>4)*4+r ; col = n0+wc*64+ni*16+(lane&15)
    #pragma unroll
    for (int mi = 0; mi < 4; ++mi) {
        #pragma unroll
        for (int ni = 0; ni < 4; ++ni) {
            const int col = n0 + wc * 64 + ni * 16 + (lane & 15);
            #pragma unroll
            for (int r = 0; r < 4; ++r) {
                const int row = m0 + wr * 64 + mi * 16 + (lane >> 4) * 4 + r;
                float v = acc[mi][ni][r];
                const long ci = (long)z * sC + (long)row * N + col;
                if constexpr (EPI == EPI_BF16_BIAS) {
                    ((bf16*)Cv)[ci] = __float2bfloat16(v + bias[col]);
                } else if constexpr (EPI == EPI_BF16_SCALE) {
                    ((bf16*)Cv)[ci] = __float2bfloat16(v * scale);
                } else if constexpr (EPI == EPI_F32) {
                    ((float*)Cv)[ci] = v;
                } else {
                    ((float*)Cv)[ci] = v + res[(long)z * sRes + (long)row * N + col];
                }
            }
        }
    }
}

// ---------------- elementwise / utility kernels ----------------

__global__ void cvt_bf16(const float* __restrict__ x, bf16* __restrict__ y, long n4) {
    long i = (long)blockIdx.x * 256 + threadIdx.x;
    if (i >= n4) return;
    float4 v = *(const float4*)&x[i * 4];
    union { bf16 h[4]; unsigned long long u; } pk;
    pk.h[0] = __float2bfloat16(v.x); pk.h[1] = __float2bfloat16(v.y);
    pk.h[2] = __float2bfloat16(v.z); pk.h[3] = __float2bfloat16(v.w);
    *(unsigned long long*)&y[i * 4] = pk.u;
}

// per z: in [R, C] -> out [C, R]; 64x64 tiles, short4 (8B) global accesses.
// R, C must be multiples of 64 (S=1024, H=768 both are).
__global__ void transpose_bf16(const bf16* __restrict__ in_, bf16* __restrict__ out_,
                               int R, int C, long sIn, long sOut)
{
    __shared__ u16 tile[64][70];    // pad 70: store-phase LDS reads <=2-way
    const u16* in  = (const u16*)in_  + (long)blockIdx.z * sIn;
    u16*       out = (u16*)out_       + (long)blockIdx.z * sOut;
    const int cb = blockIdx.x * 64, rb = blockIdx.y * 64;
    const int lx = threadIdx.x & 15, ly = threadIdx.x >> 4;
    #pragma unroll
    for (int i = 0; i < 4; ++i) {
        const int r = ly + i * 16;
        ushort4 v = *(const ushort4*)&in[(long)(rb + r) * C + cb + lx * 4];
        *(unsigned*)&tile[r][lx * 4]     = (unsigned)v.x | ((unsigned)v.y << 16);
        *(unsigned*)&tile[r][lx * 4 + 2] = (unsigned)v.z | ((unsigned)v.w << 16);
    }
    __syncthreads();
    #pragma unroll
    for (int i = 0; i < 4; ++i) {
        const int ro = ly + i * 16;
        ushort4 o;
        o.x = tile[lx * 4 + 0][ro];
        o.y = tile[lx * 4 + 1][ro];
        o.z = tile[lx * 4 + 2][ro];
        o.w = tile[lx * 4 + 3][ro];
        *(ushort4*)&out[(long)(cb + ro) * R + rb + lx * 4] = o;
    }
}

template<int W>   // row width (1024 or 768), in-place softmax over bf16 rows
__global__ void softmax_rows(bf16* __restrict__ P) {
    constexpr int NV = W / 4;                       // ushort4 chunks per row
    u16* p = (u16*)(P + (long)blockIdx.x * W);
    const int tid = threadIdx.x;
    const bool act = tid < NV;
    float v[4];
    float mx = -3.0e38f;
    if (act) {
        ushort4 u4 = ((const ushort4*)p)[tid];
        v[0] = __uint_as_float((unsigned)u4.x << 16);
        v[1] = __uint_as_float((unsigned)u4.y << 16);
        v[2] = __uint_as_float((unsigned)u4.z << 16);
        v[3] = __uint_as_float((unsigned)u4.w << 16);
        mx = fmaxf(fmaxf(v[0], v[1]), fmaxf(v[2], v[3]));
    }
    #pragma unroll
    for (int o = 32; o; o >>= 1) mx = fmaxf(mx, __shfl_xor(mx, o));
    __shared__ float sm[4], ss[4];
    if ((tid & 63) == 0) sm[tid >> 6] = mx;
    __syncthreads();
    mx = fmaxf(fmaxf(sm[0], sm[1]), fmaxf(sm[2], sm[3]));
    float s = 0.f;
    if (act) {
        #pragma unroll
        for (int j = 0; j < 4; ++j) { v[j] = __expf(v[j] - mx); s += v[j]; }
    }
    #pragma unroll
    for (int o = 32; o; o >>= 1) s += __shfl_xor(s, o);
    if ((tid & 63) == 0) ss[tid >> 6] = s;
    __syncthreads();
    s = ss[0] + ss[1] + ss[2] + ss[3];
    const float inv = 1.0f / s;
    if (act) {
        ushort4 o4;
        o4.x = f2bu(v[0] * inv);
        o4.y = f2bu(v[1] * inv);
        o4.z = f2bu(v[2] * inv);
        o4.w = f2bu(v[3] * inv);
        ((ushort4*)p)[tid] = o4;
    }
}

// per-batch LN stats (sum, sumsq) via block partials + float atomics
__global__ void ln_stats(const float* __restrict__ x, float* __restrict__ stats, int perB) {
    const int b = blockIdx.y;
    const float* xb = x + (long)b * perB;
    const int tid = threadIdx.x;
    const long base = (long)blockIdx.x * 4096;
    float s1 = 0.f, s2 = 0.f;
    #pragma unroll
    for (int i = 0; i < 4; ++i) {
        float4 v = *(const float4*)&xb[base + i * 1024 + tid * 4];
        s1 += v.x + v.y + v.z + v.w;
        s2 += v.x * v.x + v.y * v.y + v.z * v.z + v.w * v.w;
    }
    #pragma unroll
    for (int o = 32; o; o >>= 1) { s1 += __shfl_xor(s1, o); s2 += __shfl_xor(s2, o); }
    __shared__ float r1[4], r2[4];
    if ((tid & 63) == 0) { r1[tid >> 6] = s1; r2[tid >> 6] = s2; }
    __syncthreads();
    if (tid == 0) {
        atomicAdd(&stats[b * 2],     r1[0] + r1[1] + r1[2] + r1[3]);
        atomicAdd(&stats[b * 2 + 1], r2[0] + r2[1] + r2[2] + r2[3]);
    }
}

DEVI void ln_params(const float* stats, int b, float n, float& mu, float& rs) {
    mu = stats[b * 2] / n;
    float var = stats[b * 2 + 1] / n - mu * mu;
    rs = rsqrtf(fmaxf(var, 0.f) + LNEPS);
}

__global__ void ln_apply(const float* __restrict__ x, const float* __restrict__ stats,
                         bf16* __restrict__ y, int perB)
{
    const long i4 = ((long)blockIdx.x * 256 + threadIdx.x) * 4;
    const int b = (int)(i4 / perB);
    float mu, rs; ln_params(stats, b, (float)perB, mu, rs);
    float4 v = *(const float4*)&x[i4];
    union { bf16 h[4]; unsigned long long u; } pk;
    pk.h[0] = __float2bfloat16((v.x - mu) * rs);
    pk.h[1] = __float2bfloat16((v.y - mu) * rs);
    pk.h[2] = __float2bfloat16((v.z - mu) * rs);
    pk.h[3] = __float2bfloat16((v.w - mu) * rs);
    *(unsigned long long*)&y[i4] = pk.u;
}

// gate[b,s] = rs*( x[b,s,:].Wsg - mu*sum(Wsg) ) + bsg   (LN fused into the dot)
__global__ void gate_kernel(const float* __restrict__ xn, const float* __restrict__ Wsg,
                            const float* __restrict__ bsg, const float* __restrict__ stats2,
                            const float* __restrict__ sumW, float* __restrict__ gate)
{
    const long row = blockIdx.x;            // b*S + s
    const int b = (int)(row >> 10);
    const float* xr = xn + row * Hh;
    const int tid = threadIdx.x;
    float d = 0.f;
    #pragma unroll
    for (int j = 0; j < 3; ++j) d += xr[tid + j * 256] * Wsg[tid + j * 256];
    #pragma unroll
    for (int o = 32; o; o >>= 1) d += __shfl_xor(d, o);
    __shared__ float sr[4];
    if ((tid & 63) == 0) sr[tid >> 6] = d;
    __syncthreads();
    if (tid == 0) {
        float mu, rs; ln_params(stats2, b, (float)(Ss * Hh), mu, rs);
        gate[row] = rs * ((sr[0] + sr[1] + sr[2] + sr[3]) - mu * sumW[0]) + bsg[0];
    }
}

__global__ void pool_kernel(const float* __restrict__ xn, const float* __restrict__ gate,
                            const float* __restrict__ stats2, float* __restrict__ psum,
                            unsigned* __restrict__ pmax)
{
    const int b = blockIdx.y;
    const int s0 = blockIdx.x * 128;
    const int tid = threadIdx.x;
    float mu, rs; ln_params(stats2, b, (float)(Ss * Hh), mu, rs);
    const float* xb = xn + (long)b * (Ss * Hh);
    float sum[3] = {0.f, 0.f, 0.f};
    float mx[3]  = {-3e38f, -3e38f, -3e38f};
    for (int s = s0; s < s0 + 128; ++s) {
        float g = gate[(b << 10) + s];
        #pragma unroll
        for (int j = 0; j < 3; ++j) {
            float v = g * (xb[(long)s * Hh + tid + j * 256] - mu) * rs;
            sum[j] += v;
            mx[j] = fmaxf(mx[j], v);
        }
    }
    #pragma unroll
    for (int j = 0; j < 3; ++j) {
        atomicAdd(&psum[b * Hh + tid + j * 256], sum[j]);
        atomicMax(&pmax[b * Hh + tid + j * 256], fkey(mx[j]));
    }
}

__global__ void classifier(const float* __restrict__ psum, const unsigned* __restrict__ pmax,
                           const float* __restrict__ Wf, const float* __restrict__ bfn,
                           float* __restrict__ out)
{
    const int b = blockIdx.x, tid = threadIdx.x;
    float a0 = 0.f, a1 = 0.f, a2 = 0.f;
    for (int h = tid; h < Hh; h += 256) {
        float mean = psum[b * Hh + h] * (1.f / (float)Ss);
        float mxv  = funkey(pmax[b * Hh + h]);
        a0 += mean * Wf[0 * 1536 + h] + mxv * Wf[0 * 1536 + Hh + h];
        a1 += mean * Wf[1 * 1536 + h] + mxv * Wf[1 * 1536 + Hh + h];
        a2 += mean * Wf[2 * 1536 + h] + mxv * Wf[2 * 1536 + Hh + h];
    }
    #pragma unroll
    for (int o = 32; o; o >>= 1) {
        a0 += __shfl_xor(a0, o); a1 += __shfl_xor(a1, o); a2 += __shfl_xor(a2, o);
    }
    __shared__ float r[3][4];
    if ((tid & 63) == 0) { int w = tid >> 6; r[0][w] = a0; r[1][w] = a1; r[2][w] = a2; }
    __syncthreads();
    if (tid < 3) out[b * 3 + tid] = r[tid][0] + r[tid][1] + r[tid][2] + r[tid][3] + bfn[tid];
}

__global__ void init_ws(float* stats1, float* stats2, float* psum, unsigned* pmax,
                        float* sumW, const float* Wsg)
{
    const int tid = threadIdx.x;
    if (tid < 64) { stats1[tid] = 0.f; stats2[tid] = 0.f; }
    for (int i = tid; i < Bb * Hh; i += 256) { psum[i] = 0.f; pmax[i] = 0u; }
    float s = 0.f;
    for (int i = tid; i < Hh; i += 256) s += Wsg[i];
    #pragma unroll
    for (int o = 32; o; o >>= 1) s += __shfl_xor(s, o);
    __shared__ float sr[4];
    if ((tid & 63) == 0) sr[tid >> 6] = s;
    __syncthreads();
    if (tid == 0) sumW[0] = sr[0] + sr[1] + sr[2] + sr[3];
}

__global__ void sentinel_kernel(float* out, int n) {
    int i = blockIdx.x * 256 + threadIdx.x;
    if (i < n) out[i] = -12345.0f;
}

// ---------------- host launch ----------------
//
// Workspace plan (272.3 MB, verified passing in R7/R8):
//   W   : wq/wk/wv bf16               3.4 MB
//   X0  : tokens bf16 -> out_ln bf16  50.3 MB
//   X1  : Q  -> OF[lo] -> Qn  -> KnT  50.3 MB  (X1,X2 adjacent, no padding)
//   X2  : K  -> OF[hi] -> Kn  -> Sn   50.3 MB
//   X4  : VT -> QnT -> PnT            50.3 MB
//   SP  : [V|Vn in first 50.3MB] scores/P  67.1 MB
//   OF (fp32 out / out_n, 100.66 MB) == X1∪X2 exactly.

extern "C" void kernel_launch(void* const* d_in, const int* in_sizes, int n_in,
                              void* d_out, int out_size, void* d_ws, size_t ws_size,
                              hipStream_t stream)
{
    const float* tokens = (const float*)d_in[0];
    const float* Wq  = (const float*)d_in[1];
    const float* bq  = (const float*)d_in[2];
    const float* Wk  = (const float*)d_in[3];
    const float* bk  = (const float*)d_in[4];
    const float* Wv  = (const float*)d_in[5];
    const float* bv  = (const float*)d_in[6];
    const float* Wsg = (const float*)d_in[7];
    const float* bsg = (const float*)d_in[8];
    const float* Wf  = (const float*)d_in[9];
    const float* bfn = (const float*)d_in[10];
    float* out = (float*)d_out;

    const long BSH = (long)Bb * Ss * Hh;     // 25165824
    const long HH  = (long)Hh * Hh;          // 589824
    const long BSS = (long)Bb * Ss * Ss;     // 33554432
    const long SH  = (long)Ss * Hh;          // 786432
    const float SCALE = 1.0f / sqrtf((float)Hh);

    char* w = (char*)d_ws;
    size_t off = 0;
    auto alloc = [&](size_t bytes) -> void* {
        off = (off + 255) & ~(size_t)255;
        void* p = w + off;
        off += bytes;
        return p;
    };
    bf16*  wqB = (bf16*)alloc(HH * 2);
    bf16*  wkB = (bf16*)alloc(HH * 2);
    bf16*  wvB = (bf16*)alloc(HH * 2);
    bf16*  X0  = (bf16*)alloc(BSH * 2);
    bf16*  X1  = (bf16*)alloc(BSH * 2);      // BSH*2 is 256-multiple -> X2 contiguous
    bf16*  X2  = (bf16*)alloc(BSH * 2);
    bf16*  X4  = (bf16*)alloc(BSH * 2);
    bf16*  SP  = (bf16*)alloc(BSS * 2);
    float* stats1 = (float*)alloc(256);
    float* stats2 = (float*)alloc(256);
    float* sumW   = (float*)alloc(256);
    float* psum   = (float*)alloc((size_t)Bb * Hh * 4);
    unsigned* pmax = (unsigned*)alloc((size_t)Bb * Hh * 4);
    float* gate   = (float*)alloc((size_t)Bb * Ss * 4);
    const size_t need = off;
    (void)in_sizes; (void)n_in;

    if (ws_size < need) {
        // diagnostic: distinguishable clean failure instead of an OOB crash
        sentinel_kernel<<<1, 256, 0, stream>>>(out, out_size);
        return;
    }

    bf16*  tokB = X0;
    bf16*  Qb   = X1;
    bf16*  Kb   = X2;
    bf16*  Vb   = SP;          // V lives in the scores region (dead before scores write)
    bf16*  VT   = X4;
    float* OF   = (float*)X1;  // spans X1+X2 = BSH*4 bytes exactly

    init_ws<<<1, 256, 0, stream>>>(stats1, stats2, psum, pmax, sumW, Wsg);

    cvt_bf16<<<(int)(BSH / 1024), 256, 0, stream>>>(tokens, tokB, BSH / 4);
    cvt_bf16<<<(int)(HH / 1024), 256, 0, stream>>>(Wq, wqB, HH / 4);
    cvt_bf16<<<(int)(HH / 1024), 256, 0, stream>>>(Wk, wkB, HH / 4);
    cvt_bf16<<<(int)(HH / 1024), 256, 0, stream>>>(Wv, wvB, HH / 4);

    // ---- Q,K,V = tokens @ W^T + b  (bf16 out)
    {
        dim3 g(Hh / 128, (Bb * Ss) / 128, 1);
        gemm_bt<EPI_BF16_BIAS><<<g, 256, 0, stream>>>(tokB, wqB, Qb, bq, nullptr,
            Bb * Ss, Hh, Hh, 0, 0, 0, 0, 1.f);
        gemm_bt<EPI_BF16_BIAS><<<g, 256, 0, stream>>>(tokB, wkB, Kb, bk, nullptr,
            Bb * Ss, Hh, Hh, 0, 0, 0, 0, 1.f);
        gemm_bt<EPI_BF16_BIAS><<<g, 256, 0, stream>>>(tokB, wvB, Vb, bv, nullptr,
            Bb * Ss, Hh, Hh, 0, 0, 0, 0, 1.f);
    }
    // V^T per batch: [S,H] -> [H,S]   (V dead afterwards; its region joins SP)
    transpose_bf16<<<dim3(Hh / 64, Ss / 64, Bb), 256, 0, stream>>>(Vb, VT, Ss, Hh, SH, SH);

    // ---- scores = Q K^T * SCALE (bf16, overwrites V region too), softmax rows -> P
    gemm_bt<EPI_BF16_SCALE><<<dim3(Ss / 128, Ss / 128, Bb), 256, 0, stream>>>(
        Qb, Kb, SP, nullptr, nullptr, Ss, Ss, Hh, SH, SH, (long)Ss * Ss, 0, SCALE);
    softmax_rows<1024><<<Bb * Ss, 256, 0, stream>>>(SP);

    // ---- out = P @ V  (A=P [S,S], Bt=V^T [H,S]) -> fp32 OF (over Q,K regions; both dead)
    gemm_bt<EPI_F32><<<dim3(Hh / 128, Ss / 128, Bb), 256, 0, stream>>>(
        SP, VT, OF, nullptr, nullptr, Ss, Hh, Ss, (long)Ss * Ss, SH, SH, 0, 1.f);

    // ---- LN1 (OF dead after ln_apply)
    ln_stats<<<dim3(192, Bb), 256, 0, stream>>>(OF, stats1, Ss * Hh);
    ln_apply<<<(int)(BSH / 1024), 256, 0, stream>>>(OF, stats1, tokB, Ss * Hh);

    // ---- Qn,Kn,Vn = out_ln @ W^T + b   (Vn into SP region; P dead)
    bf16* Qn = X1; bf16* Kn = X2; bf16* Vn = SP;
    {
        dim3 g(Hh / 128, (Bb * Ss) / 128, 1);
        gemm_bt<EPI_BF16_BIAS><<<g, 256, 0, stream>>>(tokB, wqB, Qn, bq, nullptr,
            Bb * Ss, Hh, Hh, 0, 0, 0, 0, 1.f);
        gemm_bt<EPI_BF16_BIAS><<<g, 256, 0, stream>>>(tokB, wkB, Kn, bk, nullptr,
            Bb * Ss, Hh, Hh, 0, 0, 0, 0, 1.f);
        gemm_bt<EPI_BF16_BIAS><<<g, 256, 0, stream>>>(tokB, wvB, Vn, bv, nullptr,
            Bb * Ss, Hh, Hh, 0, 0, 0, 0, 1.f);
    }

    // ---- Qn^T -> X4 (VT dead), then Kn^T -> X1 (Qn dead)
    bf16* QnT = X4;
    bf16* KnT = X1;
    transpose_bf16<<<dim3(Hh / 64, Ss / 64, Bb), 256, 0, stream>>>(Qn, QnT, Ss, Hh, SH, SH);
    transpose_bf16<<<dim3(Hh / 64, Ss / 64, Bb), 256, 0, stream>>>(Kn, KnT, Ss, Hh, SH, SH);

    // ---- Sn = Qn^T Kn * SCALE -> [B,H,H] bf16 into X2 (Kn dead), softmax -> Pn
    bf16* Sn = X2;
    gemm_bt<EPI_BF16_SCALE><<<dim3(Hh / 128, Hh / 128, Bb), 256, 0, stream>>>(
        QnT, KnT, Sn, nullptr, nullptr, Hh, Hh, Ss, SH, SH, HH, 0, SCALE);
    softmax_rows<768><<<Bb * Hh, 256, 0, stream>>>(Sn);

    // ---- Pn^T per batch: [H,H] -> [H,H] into X4 (QnT dead)
    bf16* PnT = X4;
    transpose_bf16<<<dim3(Hh / 64, Hh / 64, Bb), 256, 0, stream>>>(Sn, PnT, Hh, Hh, HH, HH);

    // ---- out_n = Vn @ Pn + tokens -> fp32 OF2 over X1∪X2 (KnT, Pn dead)
    float* OF2 = (float*)X1;
    gemm_bt<EPI_F32_RES><<<dim3(Hh / 128, Ss / 128, Bb), 256, 0, stream>>>(
        Vn, PnT, OF2, nullptr, tokens, Ss, Hh, Hh, SH, HH, SH, SH, 1.f);

    // ---- LN2 stats, gate, pool, classifier
    ln_stats<<<dim3(192, Bb), 256, 0, stream>>>(OF2, stats2, Ss * Hh);
    gate_kernel<<<Bb * Ss, 256, 0, stream>>>(OF2, Wsg, bsg, stats2, sumW, gate);
    pool_kernel<<<dim3(Ss / 128, Bb), 256, 0, stream>>>(OF2, gate, stats2, psum, pmax);
    classifier<<<Bb, 256, 0, stream>>>(psum, pmax, Wf, bfn, out);
}